// Round 3
// 515.056 us; speedup vs baseline: 1.2742x; 1.2742x over previous
//
#include <hip/hip_runtime.h>
#include <math.h>

// Problem constants
#define H 128
#define SW 113          // 128-16+1
#define CAND_CAP 96

typedef __attribute__((ext_vector_type(8))) short short8;  // 8 bf16 (4 VGPRs)
typedef __attribute__((ext_vector_type(4))) float f32x4;   // MFMA accumulator

// fp32 -> bf16, round-to-nearest-even (matches the error analysis)
static __device__ __forceinline__ uint32_t f2bf1(float v) {
    uint32_t u = __float_as_uint(v);
    return (u + 0x7fffu + ((u >> 16) & 1u)) >> 16;
}
static __device__ __forceinline__ uint32_t pack2(float a, float b) {
    return f2bf1(a) | (f2bf1(b) << 16);
}
static __device__ __forceinline__ float bf2f(unsigned short v) {
    return __uint_as_float(((uint32_t)v) << 16);
}

// ---------------- prep: wn = w / sqrt(sum(w^2)/n), n = 16384 ----------------
__global__ __launch_bounds__(256) void prep_wn(const float* __restrict__ w,
                                               float* __restrict__ wn) {
    __shared__ float red[256];
    int t = threadIdx.x;
    float wv = w[t];
    red[t] = wv * wv;
    __syncthreads();
    for (int off = 128; off > 0; off >>= 1) {
        if (t < off) red[t] += red[t + off];
        __syncthreads();
    }
    float denom = sqrtf(red[0] / 16384.0f);
    wn[t] = wv / denom;
}

// ---------------- main ----------------
// One block (256 thr = 4 waves) per sample.
// LDS: [0..8191]   input as bf16, 128 rows x 16 chunks(16B), chunk-swizzled
//      [8192..]    scores bf16, x-major [x<113][y 0..127], chunk-swizzled
// After phase 1, the input region is aliased for reduction/candidate scratch.
__global__ __launch_bounds__(256) void gtpca_main(
    const float* __restrict__ in, const float* __restrict__ wn_g,
    float* __restrict__ out) {

    __shared__ __align__(16) uint32_t lds[15424];    // 61,696 B
    uint32_t* lds_in = lds;                      // 8192 dwords (32 KB)
    uint32_t* lds_sc = lds + 8192;               // 7232 dwords (28.25 KB)
    float* red_a  = (float*)lds;                 // [256]  (alias, post-phase-1)
    int*   cand_n = (int*)(lds + 256);
    int*   cand_i = (int*)(lds + 260);           // [CAND_CAP]
    float* cand_v = (float*)(lds + 260 + CAND_CAP);

    const int tid  = threadIdx.x;
    const int lane = tid & 63;
    const int wid  = tid >> 6;
    const int b    = blockIdx.x;
    const float* ip  = in + (size_t)b * (H * H);
    const float4* in4 = (const float4*)ip;

    // ---- B fragments in registers: B_ki[k][n] = wn[ki][k-n], 0<=k-n<16 ----
    // mfma_f32_16x16x32_bf16 B layout: lane holds n = lane&15, k = (lane>>4)*8+e
    const int n15 = lane & 15;
    const int kg  = lane >> 4;                   // 0..3
    short8 Breg[16];
#pragma unroll
    for (int ki = 0; ki < 16; ++ki) {
        short8 f;
#pragma unroll
        for (int e = 0; e < 8; ++e) {
            int d = kg * 8 + e - n15;            // k - n
            float v = ((unsigned)d < 16u) ? wn_g[ki * 16 + d] : 0.0f;
            f[e] = (short)f2bf1(v);
        }
        Breg[ki] = f;
    }

    // ---- stage input as bf16 into LDS, chunk(16B) swizzle: phys = c ^ (r&7) ----
#pragma unroll
    for (int i = 0; i < 16; ++i) {
        int g = tid + 256 * i;                   // float4 id 0..4095
        float4 v = in4[g];
        int r = g >> 5, h = g & 31;              // row, half-chunk
        int phys = (h >> 1) ^ (r & 7);
        uint2 pk = make_uint2(pack2(v.x, v.y), pack2(v.z, v.w));
        *(uint2*)(lds_in + r * 64 + phys * 4 + (h & 1) * 2) = pk;
    }
    __syncthreads();

    // ---- MFMA scores: tile (ty,tx): C = sum_ki A(rows y0+ki+m, cols 16tx+k) * B_ki ----
    const short8* ldsA = (const short8*)lds_in;  // index = r*16 + phys_chunk
#pragma unroll
    for (int tyi = 0; tyi < 2; ++tyi) {
        int ty = 2 * wid + tyi;                  // 0..7
        int rbase = 16 * ty + n15;               // A row for this lane at ki=0
#pragma unroll
        for (int hf = 0; hf < 2; ++hf) {
            f32x4 C[4];
            f32x4 Cz = {0.0f, 0.0f, 0.0f, 0.0f};
#pragma unroll
            for (int j = 0; j < 4; ++j) C[j] = Cz;
#pragma unroll
            for (int ki = 0; ki < 16; ++ki) {
                int r = rbase + ki; if (r > 127) r = 127;   // only invalid rows clamp
                int rx = r << 4, rk = r & 7;
#pragma unroll
                for (int j = 0; j < 4; ++j) {
                    int cl = 2 * (4 * hf + j) + kg;          // logical chunk
                    if (cl > 15) cl = 15;                    // tx=7 tail: B=0 kills it
                    short8 a = ldsA[rx | (cl ^ rk)];
                    C[j] = __builtin_amdgcn_mfma_f32_16x16x32_bf16(a, Breg[ki], C[j], 0, 0, 0);
                }
            }
            // C layout: col n = lane&15 -> x; row = 4*(lane>>4)+reg -> y
            int ys  = 16 * ty + 4 * kg;
            int cch = ys >> 3;
#pragma unroll
            for (int j = 0; j < 4; ++j) {
                int x = 16 * (4 * hf + j) + n15;
                if (x < SW) {
                    uint2 pk = make_uint2(pack2(C[j][0], C[j][1]),
                                          pack2(C[j][2], C[j][3]));
                    *(uint2*)(lds_sc + x * 64 + ((cch ^ (x & 15)) << 2) + (kg & 1) * 2) = pk;
                }
            }
        }
    }
    __syncthreads();

    // ---- scan 1: approximate max |score| over valid (x<113, y<113) ----
    const int sx = tid >> 1;
    const int c0 = (tid & 1) * 8;
    float best_a = -1.0f;
    if (sx < SW) {
#pragma unroll
        for (int q = 0; q < 8; ++q) {
            int cch = c0 + q;
            short8 v = *(const short8*)(lds_sc + sx * 64 + ((cch ^ (sx & 15)) << 2));
#pragma unroll
            for (int e = 0; e < 8; ++e) {
                int y = cch * 8 + e;
                float a = fabsf(bf2f((unsigned short)v[e]));
                if (y < SW && a > best_a) best_a = a;
            }
        }
    }
    if (tid == 0) *cand_n = 0;
    red_a[tid] = best_a;
    __syncthreads();
    for (int off = 128; off > 0; off >>= 1) {
        if (tid < off) red_a[tid] = fmaxf(red_a[tid], red_a[tid + off]);
        __syncthreads();
    }
    // screening margin: 2*eps_bf16 + store rounding; eps <= 2^-7*sqrt(Sa^2)*128 ~ 20
    const float tau = red_a[0] - 48.0f;

    // ---- scan 2: collect ALL candidates >= tau (complete by construction) ----
    if (sx < SW) {
#pragma unroll
        for (int q = 0; q < 8; ++q) {
            int cch = c0 + q;
            short8 v = *(const short8*)(lds_sc + sx * 64 + ((cch ^ (sx & 15)) << 2));
#pragma unroll
            for (int e = 0; e < 8; ++e) {
                int y = cch * 8 + e;
                float a = fabsf(bf2f((unsigned short)v[e]));
                if (y < SW && a >= tau) {
                    int pos = atomicAdd(cand_n, 1);
                    if (pos < CAND_CAP) cand_i[pos] = y * SW + sx;
                }
            }
        }
    }
    __syncthreads();
    int ncand = *cand_n; if (ncand > CAND_CAP) ncand = CAND_CAP;

    // ---- exact fp32 rescore (one wave per candidate, round-robin) ----
    for (int c = wid; c < ncand; c += 4) {
        int idx = cand_i[c];
        int yy = idx / SW, xx = idx - yy * SW;
        int kj = lane & 15, k0 = (lane >> 4) * 4;
        float s = 0.0f;
#pragma unroll
        for (int j2 = 0; j2 < 4; ++j2) {
            int ki = k0 + j2;
            s = __builtin_fmaf(ip[(yy + ki) * H + xx + kj], wn_g[ki * 16 + kj], s);
        }
#pragma unroll
        for (int mk = 32; mk > 0; mk >>= 1) s += __shfl_xor(s, mk, 64);
        if (lane == 0) cand_v[c] = s;
    }
    __syncthreads();

    // all threads redundantly pick best (max |v|, tie -> min idx = first occurrence)
    float bsa = -1.0f, bsv = 0.0f; int bsi = 0x7FFFFFFF;
    for (int c = 0; c < ncand; ++c) {
        float v = cand_v[c], a = fabsf(v);
        int idx = cand_i[c];
        if (a > bsa || (a == bsa && idx < bsi)) { bsa = a; bsi = idx; bsv = v; }
    }
    const int rr = bsi / SW;
    const int cc = bsi - rr * SW;
    const float sv = bsv * (1.0f / 16384.0f);    // exact: /2^14

    // ---- output: zeros + sv*wn block at (rr,cc) ----
    float4* out4 = (float4*)(out + (size_t)b * (H * H));
#pragma unroll
    for (int i = 0; i < 16; ++i) {
        int g = tid + i * 256;
        int orow = g >> 5;
        int ocol = (g & 31) << 2;
        float4 v = {0.0f, 0.0f, 0.0f, 0.0f};
        int dr = orow - rr;
        if ((unsigned)dr < 16u) {
            float* vp = (float*)&v;
#pragma unroll
            for (int k = 0; k < 4; ++k) {
                int dc = ocol + k - cc;
                if ((unsigned)dc < 16u) vp[k] = sv * wn_g[dr * 16 + dc];
            }
        }
        out4[g] = v;
    }
}

extern "C" void kernel_launch(void* const* d_in, const int* in_sizes, int n_in,
                              void* d_out, int out_size, void* d_ws, size_t ws_size,
                              hipStream_t stream) {
    const float* in = (const float*)d_in[0];   // (4096,128,128) fp32
    const float* w = (const float*)d_in[1];    // (16,16) fp32
    float* out = (float*)d_out;                // (4096,128,128) fp32
    float* wn = (float*)d_ws;                  // 256 floats scratch

    prep_wn<<<1, 256, 0, stream>>>(w, wn);
    gtpca_main<<<4096, 256, 0, stream>>>(in, wn, out);
}